// Round 1
// baseline (12515.334 us; speedup 1.0000x reference)
//
#include <hip/hip_runtime.h>
#include <hip/hip_cooperative_groups.h>

namespace cg = cooperative_groups;

#define M_ROWS 2048
#define N_COLS 4096
#define RHO_C 1.0f
#define STEP_C 5e-05f
#define MAX_ITERS_C 100
#define INNER_C 20

// Agent-scope relaxed 64-bit atomics: value+tag travel in ONE word, so the
// data load IS the synchronization — no fences, no barrier network.
__device__ __forceinline__ unsigned long long ald64(const unsigned long long* p) {
    return __hip_atomic_load(p, __ATOMIC_RELAXED, __HIP_MEMORY_SCOPE_AGENT);
}
__device__ __forceinline__ void ast64(unsigned long long* p, unsigned long long v) {
    __hip_atomic_store(p, v, __ATOMIC_RELAXED, __HIP_MEMORY_SCOPE_AGENT);
}
__device__ __forceinline__ unsigned long long packf(float f, unsigned tag) {
    union { float f; unsigned u; } c; c.f = f;
    return ((unsigned long long)tag << 32) | (unsigned long long)c.u;
}
__device__ __forceinline__ float unpackf(unsigned long long v) {
    union { unsigned u; float f; } c; c.u = (unsigned)v; return c.f;
}

// Stage full x (tagged) from slot TAG&1 into LDS xs4. Each thread owns
// entries [4*tid, 4*tid+4). Poll until all 4 tags match, then unpack.
// WAR safety vs producers is by construction: the stager of a block's own
// entries can only pass its poll after the block's own producers stored
// tag TAG, which is program-order-after their x_old reads from these slots.
#define STAGE_X(TAG)                                                         \
    {                                                                        \
        const unsigned long long* xp =                                       \
            xP + ((((unsigned)(TAG)) & 1u) << 12) + ((unsigned)tid << 2);    \
        unsigned long long w0, w1, w2, w3;                                   \
        for (;;) {                                                           \
            w0 = ald64(xp + 0); w1 = ald64(xp + 1);                          \
            w2 = ald64(xp + 2); w3 = ald64(xp + 3);                          \
            unsigned mm = ((unsigned)(w0 >> 32) ^ (unsigned)(TAG))           \
                        | ((unsigned)(w1 >> 32) ^ (unsigned)(TAG))           \
                        | ((unsigned)(w2 >> 32) ^ (unsigned)(TAG))           \
                        | ((unsigned)(w3 >> 32) ^ (unsigned)(TAG));          \
            if (mm == 0u) break;                                             \
            __builtin_amdgcn_s_sleep(1);                                     \
        }                                                                    \
        xs4[tid] = make_float4(unpackf(w0), unpackf(w1),                     \
                               unpackf(w2), unpackf(w3));                    \
    }                                                                        \
    __syncthreads();

// 256 blocks (1/CU) x 1024 threads (16 waves), persistent cooperative kernel.
// Gram form: g = c + rho*(M x - A^T rt), M = A^T A held ENTIRELY in registers.
// All cross-block exchange is tag-packed u64 data-flow; zero grid barriers
// in the main loop (the single grid.sync() only publishes init + M).
__global__ __launch_bounds__(1024) void admm_df(
    const float* __restrict__ A, const float* __restrict__ bvec,
    const float* __restrict__ cvec, float* __restrict__ out,
    unsigned long long* __restrict__ xP,   // 2 slots x 4096 packed x
    unsigned long long* __restrict__ rtP)  // 2048 packed rt (tag = outer)
{
    cg::grid_group grid = cg::this_grid();
    const int tid  = threadIdx.x;
    const int blk  = blockIdx.x;
    const int lane = tid & 63;
    const int wave = tid >> 6;
    const int cgp  = wave >> 2;   // col-group: cols [1024*cgp, +1024)
    const int rq   = wave & 3;    // row-quad : rows 16*blk + 4*rq .. +4

    __shared__ float  abuf[4 * N_COLS];  // 64 KB staging (A rows / rt)
    __shared__ float4 xs4[1024];         // 16 KB staged x
    __shared__ float  red[4][16];        // per-colgroup row partials
    __shared__ float4 gred[64];          // w-phase reduce scratch
    __shared__ float  wl[16], cw[16];
    __shared__ float  sv[8], uv[8], tpart[16];

    float* xs = reinterpret_cast<float*>(xs4);
    const float4* A4 = reinterpret_cast<const float4*>(A);
    float4* abuf4 = reinterpret_cast<float4*>(abuf);

    // ---- init (re-poisons any stale tags from a previous dispatch) ----
    if (tid < 16) {
        cw[tid] = cvec[blk * 16 + tid];
        ast64(&xP[blk * 16 + tid],        packf(0.0f, 0u));          // slot0: tag 0
        ast64(&xP[4096 + blk * 16 + tid], packf(0.0f, 0xFFFFFFFFu)); // slot1: sentinel
    }
    if (tid < 8) {
        sv[tid] = 0.0f; uv[tid] = 0.0f;
        ast64(&rtP[blk * 8 + tid], packf(bvec[blk * 8 + tid], 0u));  // rt@outer0 = b
    }

    // ---- precompute register-resident M fragment ----
    float accM[4][16];
    #pragma unroll
    for (int r = 0; r < 4; ++r)
        #pragma unroll
        for (int k = 0; k < 16; ++k) accM[r][k] = 0.0f;

    for (int i0 = 0; i0 < M_ROWS; i0 += 4) {
        #pragma unroll
        for (int ii = 0; ii < 4; ++ii)
            abuf4[ii * 1024 + tid] = A4[(size_t)(i0 + ii) * 1024 + tid];
        __syncthreads();
        #pragma unroll
        for (int ii = 0; ii < 4; ++ii) {
            const float*  row  = abuf + ii * N_COLS;
            const float4* row4 = abuf4 + ii * 1024;
            float4 av[4];
            #pragma unroll
            for (int q = 0; q < 4; ++q)
                av[q] = row4[256 * cgp + 64 * q + lane];
            float cb[4];
            #pragma unroll
            for (int r = 0; r < 4; ++r) cb[r] = row[blk * 16 + rq * 4 + r];
            #pragma unroll
            for (int r = 0; r < 4; ++r)
                #pragma unroll
                for (int q = 0; q < 4; ++q) {
                    accM[r][4 * q + 0] = fmaf(cb[r], av[q].x, accM[r][4 * q + 0]);
                    accM[r][4 * q + 1] = fmaf(cb[r], av[q].y, accM[r][4 * q + 1]);
                    accM[r][4 * q + 2] = fmaf(cb[r], av[q].z, accM[r][4 * q + 2]);
                    accM[r][4 * q + 3] = fmaf(cb[r], av[q].w, accM[r][4 * q + 3]);
                }
        }
        __syncthreads();
    }

    grid.sync();   // single cg sync: publishes init tags grid-wide

    // x tag t: consumed value; producers write tag t+1.  t runs 0..2000.
    unsigned t = 0;
    STAGE_X(0u)    // stage x@0 once; inner-0 of each outer reuses prior stage

    for (int outer = 0; outer < MAX_ITERS_C; ++outer) {
        // ---- w-phase: wl = (A^T rt)[16b..16b+16), rt via tag poll ----
        {
            const unsigned long long* rp = rtP + tid;
            unsigned long long wa, wb;
            for (;;) {
                wa = ald64(rp); wb = ald64(rp + 1024);
                unsigned mm = ((unsigned)(wa >> 32) ^ (unsigned)outer)
                            | ((unsigned)(wb >> 32) ^ (unsigned)outer);
                if (mm == 0u) break;
                __builtin_amdgcn_s_sleep(1);
            }
            abuf[tid]        = unpackf(wa);
            abuf[tid + 1024] = unpackf(wb);
        }
        __syncthreads();
        {
            const int p = tid >> 2, gq = tid & 3;
            float4 acc = {0.f, 0.f, 0.f, 0.f};
            #pragma unroll
            for (int k2 = 0; k2 < 8; ++k2) {
                const int i = p + 256 * k2;
                const float tv = abuf[i];
                float4 a = A4[(size_t)i * 1024 + blk * 4 + gq];
                acc.x = fmaf(a.x, tv, acc.x); acc.y = fmaf(a.y, tv, acc.y);
                acc.z = fmaf(a.z, tv, acc.z); acc.w = fmaf(a.w, tv, acc.w);
            }
            #pragma unroll
            for (int off = 4; off < 64; off <<= 1) {
                acc.x += __shfl_xor(acc.x, off);
                acc.y += __shfl_xor(acc.y, off);
                acc.z += __shfl_xor(acc.z, off);
                acc.w += __shfl_xor(acc.w, off);
            }
            if ((lane >> 2) == 0) gred[wave * 4 + gq] = acc;
        }
        __syncthreads();
        if (tid < 4) {
            float4 tot = {0.f, 0.f, 0.f, 0.f};
            #pragma unroll
            for (int w = 0; w < 16; ++w) {
                float4 v = gred[w * 4 + tid];
                tot.x += v.x; tot.y += v.y; tot.z += v.z; tot.w += v.w;
            }
            wl[tid * 4 + 0] = tot.x; wl[tid * 4 + 1] = tot.y;
            wl[tid * 4 + 2] = tot.z; wl[tid * 4 + 3] = tot.w;
        }
        __syncthreads();

        // ---- inner PGD: x <- relu(x - step*(c + rho*(Mx - wl))) ----
        for (int inner = 0; inner < INNER_C; ++inner) {
            if (inner != 0) { STAGE_X(t) }   // inner 0: xs4 already holds x@t

            float4 xq[4];
            #pragma unroll
            for (int q = 0; q < 4; ++q)
                xq[q] = xs4[256 * cgp + 64 * q + lane];

            float4 pd = {0.f, 0.f, 0.f, 0.f};
            #pragma unroll
            for (int q = 0; q < 4; ++q) {
                pd.x = fmaf(accM[0][4*q+0], xq[q].x, pd.x);
                pd.x = fmaf(accM[0][4*q+1], xq[q].y, pd.x);
                pd.x = fmaf(accM[0][4*q+2], xq[q].z, pd.x);
                pd.x = fmaf(accM[0][4*q+3], xq[q].w, pd.x);
                pd.y = fmaf(accM[1][4*q+0], xq[q].x, pd.y);
                pd.y = fmaf(accM[1][4*q+1], xq[q].y, pd.y);
                pd.y = fmaf(accM[1][4*q+2], xq[q].z, pd.y);
                pd.y = fmaf(accM[1][4*q+3], xq[q].w, pd.y);
                pd.z = fmaf(accM[2][4*q+0], xq[q].x, pd.z);
                pd.z = fmaf(accM[2][4*q+1], xq[q].y, pd.z);
                pd.z = fmaf(accM[2][4*q+2], xq[q].z, pd.z);
                pd.z = fmaf(accM[2][4*q+3], xq[q].w, pd.z);
                pd.w = fmaf(accM[3][4*q+0], xq[q].x, pd.w);
                pd.w = fmaf(accM[3][4*q+1], xq[q].y, pd.w);
                pd.w = fmaf(accM[3][4*q+2], xq[q].z, pd.w);
                pd.w = fmaf(accM[3][4*q+3], xq[q].w, pd.w);
            }

            #pragma unroll
            for (int off = 32; off; off >>= 1) {
                pd.x += __shfl_xor(pd.x, off);
                pd.y += __shfl_xor(pd.y, off);
                pd.z += __shfl_xor(pd.z, off);
                pd.w += __shfl_xor(pd.w, off);
            }
            if (lane == 0) {
                red[cgp][rq * 4 + 0] = pd.x;
                red[cgp][rq * 4 + 1] = pd.y;
                red[cgp][rq * 4 + 2] = pd.z;
                red[cgp][rq * 4 + 3] = pd.w;
            }
            __syncthreads();

            if (tid < 16) {
                const float y = red[0][tid] + red[1][tid]
                              + red[2][tid] + red[3][tid];
                const float g = cw[tid] + RHO_C * (y - wl[tid]);
                float xn = xs[blk * 16 + tid] - STEP_C * g;   // x_old read ...
                xn = xn > 0.f ? xn : 0.f;
                ast64(&xP[(((t + 1u) & 1u) << 12) + blk * 16 + tid],
                      packf(xn, t + 1u));                     // ... before publish
            }
            ++t;   // no barrier: next STAGE_X's tag poll IS the sync
        }

        // ---- Ax on own 8 rows + s,u,rt update; x@t via tag poll ----
        STAGE_X(t)
        {
            const int r = blk * 8 + (wave >> 1), h = wave & 1;
            const float4* Ar = A4 + (size_t)r * 1024 + h * 512;
            const float4* xh = xs4 + h * 512;
            float4 acc = {0.f, 0.f, 0.f, 0.f};
            #pragma unroll
            for (int it = 0; it < 8; ++it) {
                float4 a = Ar[it * 64 + lane], xv = xh[it * 64 + lane];
                acc.x = fmaf(a.x, xv.x, acc.x); acc.y = fmaf(a.y, xv.y, acc.y);
                acc.z = fmaf(a.z, xv.z, acc.z); acc.w = fmaf(a.w, xv.w, acc.w);
            }
            float d = acc.x + acc.y + acc.z + acc.w;
            #pragma unroll
            for (int off = 32; off; off >>= 1) d += __shfl_xor(d, off);
            if (lane == 0) tpart[wave] = d;
        }
        __syncthreads();
        if (tid < 8) {
            const int i = blk * 8 + tid;
            const float a  = tpart[2 * tid] + tpart[2 * tid + 1];
            const float bb = bvec[i];
            const float uu = uv[tid];
            float sn = a - bb + uu; sn = sn > 0.f ? sn : 0.f;
            const float un = uu + a - sn - bb;
            sv[tid] = sn; uv[tid] = un;
            ast64(&rtP[i], packf(sn + bb - un, (unsigned)outer + 1u));
        }
        // no barrier: next outer's rt tag poll IS the sync
    }

    // ---- outputs: [x(4096), s(2048), u(2048), -u(2048)] ----
    // xs4 still holds x@2000 from the final Ax stage.
    if (tid < 16) out[blk * 16 + tid] = xs[blk * 16 + tid];
    if (tid < 8) {
        const int i = blk * 8 + tid;
        out[4096 + i] = sv[tid];
        out[6144 + i] = uv[tid];
        out[8192 + i] = -uv[tid];
    }
}

extern "C" void kernel_launch(void* const* d_in, const int* in_sizes, int n_in,
                              void* d_out, int out_size, void* d_ws, size_t ws_size,
                              hipStream_t stream) {
    const float* A    = (const float*)d_in[0];   // 2048*4096
    const float* bvec = (const float*)d_in[1];   // 2048
    const float* cvec = (const float*)d_in[2];   // 4096
    float* out = (float*)d_out;

    unsigned long long* xP  = (unsigned long long*)d_ws;  // 2*4096 u64 = 64 KB
    unsigned long long* rtP = xP + 2 * 4096;              // 2048 u64  = 16 KB

    void* args[] = { (void*)&A, (void*)&bvec, (void*)&cvec, (void*)&out,
                     (void*)&xP, (void*)&rtP };
    hipError_t err = hipLaunchCooperativeKernel((const void*)admm_df,
                               dim3(256), dim3(1024), args, 0, stream);
    (void)err;
}